// Round 1
// baseline (344.028 us; speedup 1.0000x reference)
//
#include <hip/hip_runtime.h>

#define FEAT 64

// Phase 1: scatter-add h[src] rows into msg[dst], count degree.
// 64 threads (one wave-half-row... actually one full 64-lane group) per edge.
__global__ void __launch_bounds__(256)
scatter_kernel(const float* __restrict__ h, const int* __restrict__ src,
               const int* __restrict__ dst, float* __restrict__ msg,
               float* __restrict__ deg, int E)
{
    int idx  = blockIdx.x * 256 + threadIdx.x;
    int e    = idx >> 6;
    if (e >= E) return;
    int lane = idx & 63;
    int s = src[e];
    int d = dst[e];
    float v = h[(long long)s * FEAT + lane];
    atomicAdd(&msg[(long long)d * FEAT + lane], v);
    if (lane == 0) atomicAdd(&deg[d], 1.0f);
}

// Phase 2: out[n] = relu(W1 @ h[n] + W2 @ (msg[n]/max(deg,1)) + b)
// Block = 256 threads, 16 nodes/block. W (64x128) staged in LDS, rows padded
// to 129 floats: per-k read across 64 lanes hits bank (lane+k)%32 -> 2-way
// aliasing only (free). x reads are wave-uniform broadcasts.
// Each thread computes j=lane output for 4 nodes (amortizes W reads 4x).
__global__ void __launch_bounds__(256)
sage_out_kernel(const float* __restrict__ h, const float* __restrict__ msg,
                const float* __restrict__ deg, const float* __restrict__ W,
                const float* __restrict__ b, float* __restrict__ out, int N)
{
    __shared__ float Wl[64][129];
    __shared__ float xl[16][128];
    __shared__ float bl[64];

    int t = threadIdx.x;
    for (int i = t; i < 64 * 128; i += 256)
        Wl[i >> 7][i & 127] = W[i];
    if (t < 64) bl[t] = b[t];

    int node0 = blockIdx.x * 16;
    for (int i = t; i < 16 * 128; i += 256) {
        int nl = i >> 7;
        int k  = i & 127;
        int node = node0 + nl;
        float v = 0.0f;
        if (node < N) {
            if (k < 64) {
                v = h[(long long)node * 64 + k];
            } else {
                float dg  = deg[node];
                float inv = 1.0f / fmaxf(dg, 1.0f);
                v = msg[(long long)node * 64 + (k - 64)] * inv;
            }
        }
        xl[nl][k] = v;
    }
    __syncthreads();

    int lane = t & 63;
    int g    = t >> 6;
    float acc0 = bl[lane], acc1 = acc0, acc2 = acc0, acc3 = acc0;
    #pragma unroll 8
    for (int k = 0; k < 128; ++k) {
        float w = Wl[lane][k];
        acc0 += w * xl[g * 4 + 0][k];
        acc1 += w * xl[g * 4 + 1][k];
        acc2 += w * xl[g * 4 + 2][k];
        acc3 += w * xl[g * 4 + 3][k];
    }
    int nb = node0 + g * 4;
    if (nb + 0 < N) out[(long long)(nb + 0) * FEAT + lane] = fmaxf(acc0, 0.0f);
    if (nb + 1 < N) out[(long long)(nb + 1) * FEAT + lane] = fmaxf(acc1, 0.0f);
    if (nb + 2 < N) out[(long long)(nb + 2) * FEAT + lane] = fmaxf(acc2, 0.0f);
    if (nb + 3 < N) out[(long long)(nb + 3) * FEAT + lane] = fmaxf(acc3, 0.0f);
}

extern "C" void kernel_launch(void* const* d_in, const int* in_sizes, int n_in,
                              void* d_out, int out_size, void* d_ws, size_t ws_size,
                              hipStream_t stream)
{
    const float* h   = (const float*)d_in[0];
    const int*   src = (const int*)d_in[1];
    const int*   dst = (const int*)d_in[2];
    const float* W   = (const float*)d_in[3];
    const float* b   = (const float*)d_in[4];
    float* out = (float*)d_out;

    int N = in_sizes[0] / FEAT;
    int E = in_sizes[1];

    float* msg = (float*)d_ws;                 // N*64 floats
    float* deg = msg + (size_t)N * FEAT;       // N floats

    // workspace is poisoned (0xAA) before timing and NOT re-zeroed between
    // replays -> must zero every call.
    hipMemsetAsync(d_ws, 0, ((size_t)N * FEAT + N) * sizeof(float), stream);

    int sblocks = (E * 64 + 255) / 256;        // 64M threads, 4 edges/block
    scatter_kernel<<<sblocks, 256, 0, stream>>>(h, src, dst, msg, deg, E);

    int gblocks = (N + 15) / 16;
    sage_out_kernel<<<gblocks, 256, 0, stream>>>(h, msg, deg, W, b, out, N);
}

// Round 2
// 309.212 us; speedup vs baseline: 1.1126x; 1.1126x over previous
//
#include <hip/hip_runtime.h>

#define FEAT 64
#define CHUNK 1024   // counts per scan block

// ---- Pass 1: degree count (int atomics, 1 per edge) ----
__global__ void __launch_bounds__(256)
count_kernel(const int* __restrict__ dst, int* __restrict__ cnt, int E)
{
    int e = blockIdx.x * 256 + threadIdx.x;
    if (e < E) atomicAdd(&cnt[dst[e]], 1);
}

// ---- Pass 2a: per-chunk sums ----
__global__ void __launch_bounds__(256)
blocksum_kernel(const int* __restrict__ cnt, int* __restrict__ bsum, int N)
{
    __shared__ int red[256];
    int b = blockIdx.x, t = threadIdx.x;
    int base = b * CHUNK;
    int s = 0;
    for (int i = t; i < CHUNK; i += 256) {
        int idx = base + i;
        if (idx < N) s += cnt[idx];
    }
    red[t] = s; __syncthreads();
    for (int o = 128; o > 0; o >>= 1) {
        if (t < o) red[t] += red[t + o];
        __syncthreads();
    }
    if (t == 0) bsum[b] = red[0];
}

// ---- Pass 2b: exclusive scan of chunk sums (single block, B <= 256) ----
__global__ void __launch_bounds__(256)
scanbsum_kernel(int* __restrict__ bsum, int B)
{
    __shared__ int s[256];
    int t = threadIdx.x;
    int orig = (t < B) ? bsum[t] : 0;
    s[t] = orig; __syncthreads();
    for (int o = 1; o < 256; o <<= 1) {
        int v = (t >= o) ? s[t - o] : 0;
        __syncthreads();
        s[t] += v;
        __syncthreads();
    }
    if (t < B) bsum[t] = s[t] - orig;   // exclusive
}

// ---- Pass 2c: per-element exclusive offsets ----
__global__ void __launch_bounds__(256)
scatteroff_kernel(const int* __restrict__ cnt, const int* __restrict__ bsum,
                  int* __restrict__ off, int N, int E)
{
    __shared__ int s[256];
    int b = blockIdx.x, t = threadIdx.x;
    int base = b * CHUNK;
    int v0 = 0, v1 = 0, v2 = 0, v3 = 0, loc;
    {
        int i = base + t * 4;
        if (i + 0 < N) v0 = cnt[i + 0];
        if (i + 1 < N) v1 = cnt[i + 1];
        if (i + 2 < N) v2 = cnt[i + 2];
        if (i + 3 < N) v3 = cnt[i + 3];
    }
    loc = v0 + v1 + v2 + v3;
    int orig = loc;
    s[t] = loc; __syncthreads();
    for (int o = 1; o < 256; o <<= 1) {
        int u = (t >= o) ? s[t - o] : 0;
        __syncthreads();
        s[t] += u;
        __syncthreads();
    }
    int ex = s[t] - orig + bsum[b];
    int i = base + t * 4;
    if (i + 0 < N) off[i + 0] = ex; ex += v0;
    if (i + 1 < N) off[i + 1] = ex; ex += v1;
    if (i + 2 < N) off[i + 2] = ex; ex += v2;
    if (i + 3 < N) off[i + 3] = ex;
    if (b == 0 && t == 0) off[N] = E;
}

// ---- Pass 3: fill adjacency (src sorted by dst); consumes cnt down to 0 ----
__global__ void __launch_bounds__(256)
fill_kernel(const int* __restrict__ src, const int* __restrict__ dst,
            const int* __restrict__ off, int* __restrict__ cnt,
            int* __restrict__ adj, int E)
{
    int e = blockIdx.x * 256 + threadIdx.x;
    if (e < E) {
        int d = dst[e];
        int p = atomicSub(&cnt[d], 1) - 1;
        adj[off[d] + p] = src[e];
    }
}

// ---- Pass 4: fused neighbor-mean gather + [h|h_neigh] @ W.T + b, relu ----
// 256 threads, 16 nodes/block. Wave w owns nodes w*4..w*4+3; lane = feature.
__global__ void __launch_bounds__(256)
sage_fused_kernel(const float* __restrict__ h, const int* __restrict__ adj,
                  const int* __restrict__ off, const float* __restrict__ W,
                  const float* __restrict__ b, float* __restrict__ out, int N)
{
    __shared__ float Wl[64][129];   // rows padded: bank=(lane+k)%32 -> 2-way, free
    __shared__ float xl[16][128];
    __shared__ float bl[64];

    int t = threadIdx.x;
    for (int i = t; i < 64 * 128; i += 256)
        Wl[i >> 7][i & 127] = W[i];
    if (t < 64) bl[t] = b[t];

    int node0 = blockIdx.x * 16;
    int lane = t & 63, w = t >> 6;

    // self features
    for (int i = t; i < 16 * 64; i += 256) {
        int nl = i >> 6, k = i & 63;
        int node = node0 + nl;
        xl[nl][k] = (node < N) ? h[(size_t)node * FEAT + k] : 0.0f;
    }

    // neighbor mean: one wave per node (lane = feature), 4 nodes per wave
    for (int q = 0; q < 4; ++q) {
        int nl = w * 4 + q;
        int node = node0 + nl;
        float sum = 0.0f;
        int dg = 0;
        if (node < N) {
            int o0 = off[node], o1 = off[node + 1];
            dg = o1 - o0;
            int e = o0;
            for (; e + 1 < o1; e += 2) {           // 2-way unroll for load ILP
                int s0 = adj[e], s1 = adj[e + 1];
                float a0 = h[(size_t)s0 * FEAT + lane];
                float a1 = h[(size_t)s1 * FEAT + lane];
                sum += a0; sum += a1;
            }
            if (e < o1) sum += h[(size_t)adj[e] * FEAT + lane];
        }
        float inv = 1.0f / fmaxf((float)dg, 1.0f);
        xl[nl][64 + lane] = sum * inv;
    }
    __syncthreads();

    float acc0 = bl[lane], acc1 = acc0, acc2 = acc0, acc3 = acc0;
    #pragma unroll 8
    for (int k = 0; k < 128; ++k) {
        float wv = Wl[lane][k];
        acc0 += wv * xl[w * 4 + 0][k];
        acc1 += wv * xl[w * 4 + 1][k];
        acc2 += wv * xl[w * 4 + 2][k];
        acc3 += wv * xl[w * 4 + 3][k];
    }
    int nb = node0 + w * 4;
    if (nb + 0 < N) out[(size_t)(nb + 0) * FEAT + lane] = fmaxf(acc0, 0.0f);
    if (nb + 1 < N) out[(size_t)(nb + 1) * FEAT + lane] = fmaxf(acc1, 0.0f);
    if (nb + 2 < N) out[(size_t)(nb + 2) * FEAT + lane] = fmaxf(acc2, 0.0f);
    if (nb + 3 < N) out[(size_t)(nb + 3) * FEAT + lane] = fmaxf(acc3, 0.0f);
}

extern "C" void kernel_launch(void* const* d_in, const int* in_sizes, int n_in,
                              void* d_out, int out_size, void* d_ws, size_t ws_size,
                              hipStream_t stream)
{
    const float* h   = (const float*)d_in[0];
    const int*   src = (const int*)d_in[1];
    const int*   dst = (const int*)d_in[2];
    const float* W   = (const float*)d_in[3];
    const float* b   = (const float*)d_in[4];
    float* out = (float*)d_out;

    int N = in_sizes[0] / FEAT;
    int E = in_sizes[1];

    // workspace layout (ints): cnt[N] | off[N+1] | adj[E] | bsum[256]
    int* cnt  = (int*)d_ws;
    int* off  = cnt + N;
    int* adj  = off + (N + 1);
    int* bsum = adj + E;

    hipMemsetAsync(cnt, 0, (size_t)N * sizeof(int), stream);

    int eblocks = (E + 255) / 256;
    count_kernel<<<eblocks, 256, 0, stream>>>(dst, cnt, E);

    int nchunks = (N + CHUNK - 1) / CHUNK;       // 98 for N=100K (<=256)
    blocksum_kernel<<<nchunks, 256, 0, stream>>>(cnt, bsum, N);
    scanbsum_kernel<<<1, 256, 0, stream>>>(bsum, nchunks);
    scatteroff_kernel<<<nchunks, 256, 0, stream>>>(cnt, bsum, off, N, E);

    fill_kernel<<<eblocks, 256, 0, stream>>>(src, dst, off, cnt, adj, E);

    int gblocks = (N + 15) / 16;
    sage_fused_kernel<<<gblocks, 256, 0, stream>>>(h, adj, off, W, b, out, N);
}

// Round 3
// 245.718 us; speedup vs baseline: 1.4001x; 1.2584x over previous
//
#include <hip/hip_runtime.h>

#define FEAT 64
#define CHUNK 1024   // counts per scan block

// ---- Pass 1: degree count (int atomics, 1 per edge) ----
__global__ void __launch_bounds__(256)
count_kernel(const int* __restrict__ dst, int* __restrict__ cnt, int E)
{
    int e = blockIdx.x * 256 + threadIdx.x;
    if (e < E) atomicAdd(&cnt[dst[e]], 1);
}

// ---- Pass 2a: per-chunk sums ----
__global__ void __launch_bounds__(256)
blocksum_kernel(const int* __restrict__ cnt, int* __restrict__ bsum, int N)
{
    __shared__ int red[256];
    int b = blockIdx.x, t = threadIdx.x;
    int base = b * CHUNK;
    int s = 0;
    for (int i = t; i < CHUNK; i += 256) {
        int idx = base + i;
        if (idx < N) s += cnt[idx];
    }
    red[t] = s; __syncthreads();
    for (int o = 128; o > 0; o >>= 1) {
        if (t < o) red[t] += red[t + o];
        __syncthreads();
    }
    if (t == 0) bsum[b] = red[0];
}

// ---- Pass 2b: exclusive scan of chunk sums (single block, B <= 256) ----
__global__ void __launch_bounds__(256)
scanbsum_kernel(int* __restrict__ bsum, int B)
{
    __shared__ int s[256];
    int t = threadIdx.x;
    int orig = (t < B) ? bsum[t] : 0;
    s[t] = orig; __syncthreads();
    for (int o = 1; o < 256; o <<= 1) {
        int v = (t >= o) ? s[t - o] : 0;
        __syncthreads();
        s[t] += v;
        __syncthreads();
    }
    if (t < B) bsum[t] = s[t] - orig;   // exclusive
}

// ---- Pass 2c: per-element exclusive offsets ----
__global__ void __launch_bounds__(256)
scatteroff_kernel(const int* __restrict__ cnt, const int* __restrict__ bsum,
                  int* __restrict__ off, int N, int E)
{
    __shared__ int s[256];
    int b = blockIdx.x, t = threadIdx.x;
    int base = b * CHUNK;
    int v0 = 0, v1 = 0, v2 = 0, v3 = 0;
    {
        int i = base + t * 4;
        if (i + 0 < N) v0 = cnt[i + 0];
        if (i + 1 < N) v1 = cnt[i + 1];
        if (i + 2 < N) v2 = cnt[i + 2];
        if (i + 3 < N) v3 = cnt[i + 3];
    }
    int loc = v0 + v1 + v2 + v3;
    int orig = loc;
    s[t] = loc; __syncthreads();
    for (int o = 1; o < 256; o <<= 1) {
        int u = (t >= o) ? s[t - o] : 0;
        __syncthreads();
        s[t] += u;
        __syncthreads();
    }
    int ex = s[t] - orig + bsum[b];
    int i = base + t * 4;
    if (i + 0 < N) off[i + 0] = ex; ex += v0;
    if (i + 1 < N) off[i + 1] = ex; ex += v1;
    if (i + 2 < N) off[i + 2] = ex; ex += v2;
    if (i + 3 < N) off[i + 3] = ex;
    if (b == 0 && t == 0) off[N] = E;
}

// ---- Pass 3: fill adjacency (src grouped by dst); consumes cnt to 0 ----
__global__ void __launch_bounds__(256)
fill_kernel(const int* __restrict__ src, const int* __restrict__ dst,
            const int* __restrict__ off, int* __restrict__ cnt,
            int* __restrict__ adj, int E)
{
    int e = blockIdx.x * 256 + threadIdx.x;
    if (e < E) {
        int d = dst[e];
        int p = atomicSub(&cnt[d], 1) - 1;
        adj[off[d] + p] = src[e];
    }
}

// ---- Pass 4: fused neighbor-mean gather + [h|h_neigh] @ W.T + b, relu ----
// 256 threads, 32 nodes/block. Gather: lane = (nbr-slot 0..3, f4 0..15) so
// one wave pulls 4 full 256B rows per global_load_dwordx4, unroll x2 -> 8
// rows in flight/wave; slot reduce via 2 shfl_xor. GEMM: lane = output j,
// 8 nodes/wave, float4 LDS reads + component partial accumulators.
__global__ void __launch_bounds__(256)
sage_fused2_kernel(const float* __restrict__ h, const int* __restrict__ adj,
                   const int* __restrict__ off, const float* __restrict__ W,
                   const float* __restrict__ bias, float* __restrict__ out, int N)
{
    __shared__ float Wl[64][132];   // pad 132: b128 reads conflict-minimal
    __shared__ float xl[32][128];   // GEMM reads are wave-uniform broadcasts
    __shared__ float bl[64];

    int t = threadIdx.x;
    // stage W (64x128 -> rows padded to 132), vectorized
    {
        const float4* W4 = (const float4*)W;
        for (int i = t; i < 64 * 32; i += 256) {
            float4 v = W4[i];
            int j = i >> 5, k4 = i & 31;
            *(float4*)&Wl[j][k4 * 4] = v;
        }
    }
    if (t < 64) bl[t] = bias[t];

    int node0 = blockIdx.x * 32;
    int lane = t & 63, w = t >> 6;

    // stage self features: 32 nodes x 16 float4
    for (int i = t; i < 512; i += 256) {
        int n = i >> 4, f4i = i & 15;
        int node = node0 + n;
        float4 v = make_float4(0.f, 0.f, 0.f, 0.f);
        if (node < N) v = *(const float4*)&h[(size_t)node * FEAT + f4i * 4];
        *(float4*)&xl[n][f4i * 4] = v;
    }

    // neighbor means: wave w owns nodes w*8..w*8+7
    int sub = lane >> 4;     // neighbor slot 0..3
    int f4  = lane & 15;     // float4 index within row
    for (int q = 0; q < 8; ++q) {
        int node = node0 + w * 8 + q;
        float s0 = 0.f, s1 = 0.f, s2 = 0.f, s3 = 0.f;
        int dg = 0;
        if (node < N) {
            int o0 = off[node], o1 = off[node + 1];
            dg = o1 - o0;
            for (int base = o0; base < o1; base += 8) {
                int e0 = base + sub, e1 = base + 4 + sub;
                if (e0 < o1) {
                    float4 v = *(const float4*)&h[(size_t)adj[e0] * FEAT + f4 * 4];
                    s0 += v.x; s1 += v.y; s2 += v.z; s3 += v.w;
                }
                if (e1 < o1) {
                    float4 v = *(const float4*)&h[(size_t)adj[e1] * FEAT + f4 * 4];
                    s0 += v.x; s1 += v.y; s2 += v.z; s3 += v.w;
                }
            }
        }
        // reduce across the 4 neighbor slots (lanes differing in bits 4,5)
        s0 += __shfl_xor(s0, 16); s0 += __shfl_xor(s0, 32);
        s1 += __shfl_xor(s1, 16); s1 += __shfl_xor(s1, 32);
        s2 += __shfl_xor(s2, 16); s2 += __shfl_xor(s2, 32);
        s3 += __shfl_xor(s3, 16); s3 += __shfl_xor(s3, 32);
        float inv = 1.0f / fmaxf((float)dg, 1.0f);
        if (sub == 0) {
            float4 m = make_float4(s0 * inv, s1 * inv, s2 * inv, s3 * inv);
            *(float4*)&xl[w * 8 + q][64 + f4 * 4] = m;
        }
    }
    __syncthreads();

    // GEMM: lane = output j; wave w computes nodes w*8..w*8+7
    float4 acc[8];
    #pragma unroll
    for (int q = 0; q < 8; ++q) acc[q] = make_float4(0.f, 0.f, 0.f, 0.f);
    #pragma unroll 4
    for (int k4 = 0; k4 < 32; ++k4) {
        float4 wv = *(const float4*)&Wl[lane][k4 * 4];
        #pragma unroll
        for (int q = 0; q < 8; ++q) {
            float4 xv = *(const float4*)&xl[w * 8 + q][k4 * 4];
            acc[q].x += wv.x * xv.x;
            acc[q].y += wv.y * xv.y;
            acc[q].z += wv.z * xv.z;
            acc[q].w += wv.w * xv.w;
        }
    }
    #pragma unroll
    for (int q = 0; q < 8; ++q) {
        int n = node0 + w * 8 + q;
        if (n < N) {
            float r = acc[q].x + acc[q].y + acc[q].z + acc[q].w + bl[lane];
            out[(size_t)n * FEAT + lane] = fmaxf(r, 0.0f);
        }
    }
}

extern "C" void kernel_launch(void* const* d_in, const int* in_sizes, int n_in,
                              void* d_out, int out_size, void* d_ws, size_t ws_size,
                              hipStream_t stream)
{
    const float* h   = (const float*)d_in[0];
    const int*   src = (const int*)d_in[1];
    const int*   dst = (const int*)d_in[2];
    const float* W   = (const float*)d_in[3];
    const float* b   = (const float*)d_in[4];
    float* out = (float*)d_out;

    int N = in_sizes[0] / FEAT;
    int E = in_sizes[1];

    // workspace (ints): cnt[N] | off[N+1] | adj[E] | bsum[256]  (~4.8 MB)
    int* cnt  = (int*)d_ws;
    int* off  = cnt + N;
    int* adj  = off + (N + 1);
    int* bsum = adj + E;

    hipMemsetAsync(cnt, 0, (size_t)N * sizeof(int), stream);

    int eblocks = (E + 255) / 256;
    count_kernel<<<eblocks, 256, 0, stream>>>(dst, cnt, E);

    int nchunks = (N + CHUNK - 1) / CHUNK;       // 98 for N=100K
    blocksum_kernel<<<nchunks, 256, 0, stream>>>(cnt, bsum, N);
    scanbsum_kernel<<<1, 256, 0, stream>>>(bsum, nchunks);
    scatteroff_kernel<<<nchunks, 256, 0, stream>>>(cnt, bsum, off, N, E);

    fill_kernel<<<eblocks, 256, 0, stream>>>(src, dst, off, cnt, adj, E);

    int gblocks = (N + 31) / 32;
    sage_fused2_kernel<<<gblocks, 256, 0, stream>>>(h, adj, off, W, b, out, N);
}